// Round 13
// baseline (435.514 us; speedup 1.0000x reference)
//
#include <hip/hip_runtime.h>
#include <hip/hip_bf16.h>

typedef __attribute__((ext_vector_type(4))) float f32x4;
typedef __attribute__((ext_vector_type(8))) short s16x8;
typedef __attribute__((ext_vector_type(4))) unsigned short u16x4;
typedef __attribute__((ext_vector_type(8))) __bf16 bf16x8;

#define B_      32
#define S_      128
#define SEQ     129
#define IN_DIM  1024
#define HD      1024
#define NHEAD   8
#define DH      128
#define OUT_DIM 256
#define KC      10
#define DFF     2048
#define MROWS   (B_*SEQ)     // 4128
#define MPAD    4224         // 33 * 128
#define NCAND   (B_*S_*KC)   // 40960 = 640*64

__device__ __forceinline__ short f2bf(float f) {
  unsigned u = __builtin_bit_cast(unsigned, f);
  u += 0x7FFFu + ((u >> 16) & 1u);   // RNE to bf16
  return (short)(u >> 16);
}
__device__ __forceinline__ float bf2f(short s) {
  return __builtin_bit_cast(float, ((unsigned)(unsigned short)s) << 16);
}
__device__ __forceinline__ void gload16(const short* g, short* l) {
  __builtin_amdgcn_global_load_lds(
      (const __attribute__((address_space(1))) unsigned*)g,
      (__attribute__((address_space(3))) unsigned*)l, 16, 0, 0);
}
// builtin MFMA: compiler-managed hazards (inline asm hid them -> NaN, r11)
__device__ __forceinline__ f32x4 mfma16(s16x8 a, s16x8 b, f32x4 c) {
  return __builtin_amdgcn_mfma_f32_16x16x32_bf16(
      __builtin_bit_cast(bf16x8, a), __builtin_bit_cast(bf16x8, b), c, 0, 0, 0);
}

// ---------------- ALL weight transposes fused: W[K][N] f32 -> Wt[N][K] bf16 --
__global__ __launch_bounds__(256) void transpose_all(
    const float* __restrict__ W_in,  const float* __restrict__ Wqkv,
    const float* __restrict__ Wo,    const float* __restrict__ W1,
    const float* __restrict__ W2,    const float* __restrict__ W_out,
    const float* __restrict__ dsW1,
    short* __restrict__ WinT,  short* __restrict__ WqkvT,
    short* __restrict__ WoT,   short* __restrict__ W1T,
    short* __restrict__ W2T,   short* __restrict__ WoutT,
    short* __restrict__ dsW1T) {
  const int b = blockIdx.x;
  const float* src; short* dst; int K, N, local;
  if (b < 1024)       { src = W_in;  dst = WinT;  K = 1024; N = 1024; local = b; }
  else if (b < 7168)  { int l = (b - 1024) / 3072; local = (b - 1024) % 3072;
                        src = Wqkv + (size_t)l * 1024 * 3072;
                        dst = WqkvT + (size_t)l * 3072 * 1024; K = 1024; N = 3072; }
  else if (b < 9216)  { int l = (b - 7168) / 1024; local = (b - 7168) % 1024;
                        src = Wo + (size_t)l * 1024 * 1024;
                        dst = WoT + (size_t)l * 1024 * 1024; K = 1024; N = 1024; }
  else if (b < 13312) { int l = (b - 9216) / 2048; local = (b - 9216) % 2048;
                        src = W1 + (size_t)l * 1024 * 2048;
                        dst = W1T + (size_t)l * 2048 * 1024; K = 1024; N = 2048; }
  else if (b < 17408) { int l = (b - 13312) / 2048; local = (b - 13312) % 2048;
                        src = W2 + (size_t)l * 2048 * 1024;
                        dst = W2T + (size_t)l * 1024 * 2048; K = 2048; N = 1024; }
  else if (b < 17664) { local = b - 17408; src = W_out; dst = WoutT; K = 1024; N = 256; }
  else                { local = b - 17664; src = dsW1;  dst = dsW1T; K = 256;  N = 256; }
  const int tilesX = N >> 5;
  const int n0 = (local % tilesX) << 5, k0 = (local / tilesX) << 5;

  __shared__ float tile[32][33];
  const int tx = threadIdx.x & 31, ty = threadIdx.x >> 5;  // 32 x 8
#pragma unroll
  for (int i = 0; i < 4; ++i)
    tile[ty + i * 8][tx] = src[(size_t)(k0 + ty + i * 8) * N + n0 + tx];
  __syncthreads();
#pragma unroll
  for (int i = 0; i < 4; ++i)
    dst[(size_t)(n0 + ty + i * 8) * K + k0 + tx] = f2bf(tile[tx][ty + i * 8]);
}

// ---------------- GEMM: C[M][N] = A[M][K](bf16) * Bt[N][K](bf16) + bias ------
// 128x128 tile, 4 waves, BK=32, 2-phase LDS double-buffer via global_load_lds
// with pre-swizzled source. Counted s_waitcnt vmcnt(4) + raw s_barrier:
// refill loads stay in flight through the next compute (no vmcnt(0) drain
// mid-loop). XCD-chunked (m204) + groupM order.
// SPLIT=true: grid gm*gn*nsplit; each split computes kper K-columns and
// writes f32 partials to P[split][MPAD][N] (no bias).
template <int EPI, bool SPLIT, typename OutT>
__global__ __launch_bounds__(256) void gemm_bt(const short* __restrict__ A,
                                               const short* __restrict__ Bt,
                                               const float* __restrict__ bias,
                                               OutT* __restrict__ C,
                                               float* __restrict__ P,
                                               int M, int N, int K,
                                               int gm, int gn, int groupM,
                                               int kper) {
  __shared__ alignas(16) short As0[4096], As1[4096];  // 128 rows x 32 bf16
  __shared__ alignas(16) short Bs0[4096], Bs1[4096];
  const int tid = threadIdx.x;
  const int lane = tid & 63, wave = tid >> 6;
  const int wr = wave >> 1, wc = wave & 1;          // 2x2 waves, 64x64 each

  // --- split decode (split-major) + XCD-chunked bijective remap (m204) ------
  const int nwg = gm * gn;
  int orig = blockIdx.x;
  int split = 0;
  if constexpr (SPLIT) { split = orig / nwg; orig %= nwg; }
  const int xcd = orig & 7, kk = orig >> 3;
  const int q = nwg >> 3, r = nwg & 7;
  const int wg = (xcd < r ? xcd * (q + 1) : r * (q + 1) + (xcd - r) * q) + kk;
  const int tpg = groupM * gn;
  const int grp = wg / tpg, rem = wg % tpg;
  const int g0 = grp * groupM;
  const int gsz = (groupM < gm - g0) ? groupM : (gm - g0);
  const int bm = (g0 + rem % gsz) * 128;
  const int bn = (rem / gsz) * 128;
  const int kbase = SPLIT ? split * kper : 0;

  // staging: pre-swizzled global source, linear LDS dest (global_load_lds).
  const short* pa[2];
  const short* pb[2];
#pragma unroll
  for (int i = 0; i < 2; ++i) {
    const int idx = i * 256 + tid;
    const int rr = idx >> 2, ss = idx & 3, gg = ss ^ ((rr >> 1) & 3);
    pa[i] = A + (size_t)(bm + rr) * K + kbase + gg * 8;
    pb[i] = Bt + (size_t)(bn + rr) * K + kbase + gg * 8;
  }

  auto stage = [&](short* aBuf, short* bBuf, int t) {
    const int kofs = t << 5;
    gload16(pa[0] + kofs, aBuf + wave * 512);
    gload16(pa[1] + kofs, aBuf + 2048 + wave * 512);
    gload16(pb[0] + kofs, bBuf + wave * 512);
    gload16(pb[1] + kofs, bBuf + 2048 + wave * 512);
  };

  // fragment reads (swizzled): row rr, k-slot ks -> shorts rr*32 + ((ks^sx)<<3)
  const int lrow = lane & 15, ks = lane >> 4;
  const int sx = (lrow >> 1) & 3;
  const int koff = ((ks ^ sx) << 3);

  f32x4 acc[4][4] = {};

  auto compute = [&](const short* as, const short* bs) {
    s16x8 af[4], bfr[4];
#pragma unroll
    for (int m = 0; m < 4; ++m)
      af[m] = *(const s16x8*)&as[(wr * 64 + m * 16 + lrow) * 32 + koff];
#pragma unroll
    for (int n = 0; n < 4; ++n)
      bfr[n] = *(const s16x8*)&bs[(wc * 64 + n * 16 + lrow) * 32 + koff];
#pragma unroll
    for (int m = 0; m < 4; ++m)
#pragma unroll
      for (int n = 0; n < 4; ++n)
        asm("v_mfma_f32_16x16x32_bf16 %0, %1, %2, %0"
            : "+v"(acc[m][n]) : "v"(af[m]), "v"(bfr[n]));
  };

  const int NT = (SPLIT ? kper : K) >> 5;   // even, >= 8 at all call sites
  stage(As0, Bs0, 0);                       // vm = 4
  stage(As1, Bs1, 1);                       // vm = 8
  asm volatile("s_waitcnt vmcnt(4)" ::: "memory");   // tile 0 landed
  __builtin_amdgcn_s_barrier();
  for (int t = 0; t < NT; t += 2) {
    compute(As0, Bs0);                      // tile t
    __builtin_amdgcn_s_barrier();           // all waves done reading As0/Bs0
    if (t + 2 < NT) {
      stage(As0, Bs0, t + 2);               // refill; stays in flight
      asm volatile("s_waitcnt vmcnt(4)" ::: "memory");  // tile t+1 landed
    } else {
      asm volatile("s_waitcnt vmcnt(0)" ::: "memory");  // tail drain
    }
    __builtin_amdgcn_s_barrier();
    compute(As1, Bs1);                      // tile t+1
    __builtin_amdgcn_s_barrier();
    if (t + 3 < NT) {
      stage(As1, Bs1, t + 3);
      asm volatile("s_waitcnt vmcnt(4)" ::: "memory");  // tile t+2 landed
    } else {
      asm volatile("s_waitcnt vmcnt(0)" ::: "memory");
    }
    __builtin_amdgcn_s_barrier();
  }

  const int lg4 = ks << 2;
#pragma unroll
  for (int n = 0; n < 4; ++n) {
    const int col = bn + wc * 64 + n * 16 + lrow;
    const float bvx = SPLIT ? 0.f : bias[col];
#pragma unroll
    for (int m = 0; m < 4; ++m) {
#pragma unroll
      for (int r2 = 0; r2 < 4; ++r2) {
        const int row = bm + wr * 64 + m * 16 + lg4 + r2;
        if constexpr (SPLIT) {
          P[((size_t)split * MPAD + row) * N + col] = acc[m][n][r2];
        } else {
          if (row < M) {
            float v = acc[m][n][r2] + bvx;
            if (EPI == 1) v = fmaxf(v, 0.f);
            if constexpr (__is_same(OutT, float)) {
              C[(size_t)row * N + col] = v;
            } else {
              C[(size_t)row * N + col] = f2bf(v);
            }
          }
        }
      }
    }
  }
}

// ---------------- reduce split-K partials: out = f(sum_s P[s] + bias) --------
template <int EPI, typename OutT>
__global__ __launch_bounds__(256) void reduce_cast(const float* __restrict__ P,
                                                   const float* __restrict__ bias,
                                                   OutT* __restrict__ out,
                                                   int N, int nsplit) {
  const int row = blockIdx.x;            // 0..MROWS-1
  for (int c = threadIdx.x * 4; c < N; c += 1024) {
    f32x4 s = *(const f32x4*)(P + (size_t)row * N + c);
    for (int sp = 1; sp < nsplit; ++sp)
      s += *(const f32x4*)(P + ((size_t)sp * MPAD + row) * N + c);
    s += *(const f32x4*)(bias + c);
    if (EPI == 1) {
      s.x = fmaxf(s.x, 0.f); s.y = fmaxf(s.y, 0.f);
      s.z = fmaxf(s.z, 0.f); s.w = fmaxf(s.w, 0.f);
    }
    if constexpr (__is_same(OutT, float)) {
      *(f32x4*)(out + (size_t)row * N + c) = s;
    } else {
      u16x4 y;
      y.x = (unsigned short)f2bf(s.x); y.y = (unsigned short)f2bf(s.y);
      y.z = (unsigned short)f2bf(s.z); y.w = (unsigned short)f2bf(s.w);
      *(u16x4*)(out + (size_t)row * N + c) = y;
    }
  }
}

// ---- fused: h = LN(h + (P0+P1 + bias)) * g + b  (split-K reduce + add+LN) ---
__global__ __launch_bounds__(256) void reduce_ln(const float* __restrict__ P,
                                                 const float* __restrict__ bias,
                                                 const float* __restrict__ g,
                                                 const float* __restrict__ bb,
                                                 short* __restrict__ h) {
  const int r = blockIdx.x, tid = threadIdx.x;
  f32x4 s = *(const f32x4*)(P + (size_t)r * 1024 + tid * 4);
  s += *(const f32x4*)(P + ((size_t)MPAD + r) * 1024 + tid * 4);
  s += *(const f32x4*)(bias + tid * 4);
  const u16x4 hv = *(const u16x4*)(h + (size_t)r * 1024 + tid * 4);
  float s0 = s.x + bf2f((short)hv.x);
  float s1 = s.y + bf2f((short)hv.y);
  float s2 = s.z + bf2f((short)hv.z);
  float s3 = s.w + bf2f((short)hv.w);
  float ls = s0 + s1 + s2 + s3;
  float l2 = s0 * s0 + s1 * s1 + s2 * s2 + s3 * s3;
#pragma unroll
  for (int off = 32; off > 0; off >>= 1) {
    ls += __shfl_down(ls, off);
    l2 += __shfl_down(l2, off);
  }
  __shared__ float red[8];
  const int wave = tid >> 6, lane = tid & 63;
  if (lane == 0) { red[wave * 2] = ls; red[wave * 2 + 1] = l2; }
  __syncthreads();
  if (tid == 0) {
    float a = 0.f, b2 = 0.f;
    for (int w = 0; w < 4; ++w) { a += red[w * 2]; b2 += red[w * 2 + 1]; }
    red[0] = a; red[1] = b2;
  }
  __syncthreads();
  const float mean = red[0] * (1.f / HD);
  const float var  = red[1] * (1.f / HD) - mean * mean;
  const float inv  = rsqrtf(var + 1e-5f);
  const f32x4 gv = *(const f32x4*)(g + tid * 4);
  const f32x4 bv = *(const f32x4*)(bb + tid * 4);
  u16x4 y;
  y.x = (unsigned short)f2bf((s0 - mean) * inv * gv.x + bv.x);
  y.y = (unsigned short)f2bf((s1 - mean) * inv * gv.y + bv.y);
  y.z = (unsigned short)f2bf((s2 - mean) * inv * gv.z + bv.z);
  y.w = (unsigned short)f2bf((s3 - mean) * inv * gv.w + bv.w);
  *(u16x4*)(h + (size_t)r * 1024 + tid * 4) = y;
}

// ---- Wout reduce (4 splits, N=256) -> pred (d_out) only --------------------
__global__ __launch_bounds__(64) void reduce_wout(const float* __restrict__ P,
                                                  const float* __restrict__ bias,
                                                  float* __restrict__ pred) {
  const int r = blockIdx.x;
  const int b = r / SEQ, t = r % SEQ;
  if (t == 0) return;                    // ctx row: not part of pred
  const int c = threadIdx.x * 4;
  f32x4 s = *(const f32x4*)(P + (size_t)r * 256 + c);
  s += *(const f32x4*)(P + ((size_t)MPAD + r) * 256 + c);
  s += *(const f32x4*)(P + ((size_t)2 * MPAD + r) * 256 + c);
  s += *(const f32x4*)(P + ((size_t)3 * MPAD + r) * 256 + c);
  s += *(const f32x4*)(bias + c);
  *(f32x4*)(pred + ((size_t)b * S_ + (t - 1)) * 256 + c) = s;
}

// ---------------- build h_in = concat([ctx, x], axis=1) -> bf16 --------------
__global__ __launch_bounds__(256) void build_hin(const float* __restrict__ x,
                                                 const float* __restrict__ ctx,
                                                 short* __restrict__ hin) {
  const int r = blockIdx.x;
  const int b = r / SEQ, t = r % SEQ;
  const float* src = (t == 0) ? (ctx + (size_t)b * IN_DIM)
                              : (x + ((size_t)b * S_ + (t - 1)) * IN_DIM);
  f32x4 v = *(const f32x4*)(src + threadIdx.x * 4);
  u16x4 o;
  o.x = (unsigned short)f2bf(v.x); o.y = (unsigned short)f2bf(v.y);
  o.z = (unsigned short)f2bf(v.z); o.w = (unsigned short)f2bf(v.w);
  *(u16x4*)(hin + (size_t)r * IN_DIM + threadIdx.x * 4) = o;
}

// ---------------- MFMA attention: ONE WAVE per (t, head), no barriers -------
__global__ __launch_bounds__(256) void attention_mfma(const short* __restrict__ qkv,
                                                      short* __restrict__ o) {
  __shared__ alignas(16) short qs[4][32][136];
  __shared__ alignas(16) short ksb[4][32][136];
  __shared__ alignas(16) short vsb[4][32][136];
  __shared__ float psb[4][32][33];
  const int tid = threadIdx.x, lane = tid & 63, w = tid >> 6;
  const int gw = blockIdx.x * 4 + w;                 // 0..1031
  const int t = gw >> 3, hd = gw & 7;
  short (*q)[136] = qs[w];
  short (*k)[136] = ksb[w];
  short (*v)[136] = vsb[w];
  float (*ps)[33] = psb[w];

  // load Q,K,V rows (bb = batch 0..31) for this (t, head)
#pragma unroll
  for (int c = lane; c < 512; c += 64) {             // 8 iters
    const int bb = c >> 4, d8 = (c & 15) << 3;
    const size_t base = ((size_t)(bb * SEQ + t)) * (3 * HD) + hd * DH + d8;
    *(s16x8*)&q[bb][d8] = *(const s16x8*)(qkv + base);
    *(s16x8*)&k[bb][d8] = *(const s16x8*)(qkv + base + HD);
    *(s16x8*)&v[bb][d8] = *(const s16x8*)(qkv + base + 2 * HD);
  }

  const int lrow = lane & 15, ksl = lane >> 4;
  const float scale = 0.08838834764831845f;          // 1/sqrt(128)

  // ---- QK^T: C[i][j] = sum_d Q[i][d] K[j][d]  (M=32, N=32, K=128) ----------
  f32x4 pacc[2][2] = {};
#pragma unroll
  for (int kst = 0; kst < 4; ++kst) {
    s16x8 aq[2], bk[2];
#pragma unroll
    for (int m = 0; m < 2; ++m)
      aq[m] = *(const s16x8*)&q[m * 16 + lrow][kst * 32 + ksl * 8];
#pragma unroll
    for (int n = 0; n < 2; ++n)
      bk[n] = *(const s16x8*)&k[n * 16 + lrow][kst * 32 + ksl * 8];
#pragma unroll
    for (int m = 0; m < 2; ++m)
#pragma unroll
      for (int n = 0; n < 2; ++n)
        pacc[m][n] = mfma16(aq[m], bk[n], pacc[m][n]);
  }
#pragma unroll
  for (int m = 0; m < 2; ++m)
#pragma unroll
    for (int n = 0; n < 2; ++n)
#pragma unroll
      for (int r = 0; r < 4; ++r)
        ps[m * 16 + ksl * 4 + r][n * 16 + lrow] = pacc[m][n][r] * scale;

  // ---- softmax per row (lanes 0..31, intra-wave ordered) -------------------
  if (lane < 32) {
    float mx = -1e30f;
#pragma unroll
    for (int j = 0; j < 32; ++j) mx = fmaxf(mx, ps[lane][j]);
    float sum = 0.f;
    float e[32];
#pragma unroll
    for (int j = 0; j < 32; ++j) { e[j] = __expf(ps[lane][j] - mx); sum += e[j]; }
    const float inv = 1.f / sum;
#pragma unroll
    for (int j = 0; j < 32; ++j) ps[lane][j] = e[j] * inv;
  }

  // ---- PV: O[i][d] = sum_j P[i][j] V[j][d]  (M=32, N=128, K=32) ------------
  s16x8 pa[2];
#pragma unroll
  for (int m = 0; m < 2; ++m) {
    const float* pr = &ps[m * 16 + lrow][ksl * 8];
#pragma unroll
    for (int j = 0; j < 8; ++j) pa[m][j] = f2bf(pr[j]);
  }
  f32x4 oacc[2][8] = {};
#pragma unroll
  for (int n = 0; n < 8; ++n) {
    s16x8 bv;
#pragma unroll
    for (int r = 0; r < 8; ++r)
      bv[r] = v[ksl * 8 + r][n * 16 + lrow];
#pragma unroll
    for (int m = 0; m < 2; ++m)
      oacc[m][n] = mfma16(pa[m], bv, oacc[m][n]);
  }
#pragma unroll
  for (int m = 0; m < 2; ++m)
#pragma unroll
    for (int n = 0; n < 8; ++n)
#pragma unroll
      for (int r = 0; r < 4; ++r) {
        const int i = m * 16 + ksl * 4 + r;
        const int d = n * 16 + lrow;
        o[((size_t)(i * SEQ + t)) * HD + hd * DH + d] = f2bf(oacc[m][n][r]);
      }
}

// ---- fused candidate scorer: gather KB rows, write cand_out[..,1:],
//      d = cand - pred -> swizzled LDS, t1 = relu(d @ dsW1 + b1) (MFMA),
//      cand_out[row*257] = t1 . w2 + b2. Block = 64 cand rows, 4 waves. ------
__global__ __launch_bounds__(256) void cand_score(
    const float* __restrict__ pred, const int* __restrict__ indices,
    const float* __restrict__ KB, const short* __restrict__ W1T,
    const float* __restrict__ b1v, const float* __restrict__ w2v,
    const float* __restrict__ b2v, float* __restrict__ cand_out) {
  __shared__ alignas(16) short Asw[8 * 2048];        // [kslice][64 rows][32] 32KB
  __shared__ alignas(16) short Bs0[8192], Bs1[8192]; // 16KB each
  __shared__ float red[64];
  const int tid = threadIdx.x;
  const int lane = tid & 63, wave = tid >> 6;        // 4 waves; wave = col-block
  const int lrow = lane & 15, ks = lane >> 4;
  const int sx = (lrow >> 1) & 3;
  const int koff = ((ks ^ sx) << 3);
  const int r0 = blockIdx.x << 6;

  // ---- gather + diff + swizzled A write + cand_out write (coalesced) ------
  {
    const int l4 = lane << 2;                        // col base 0..252
    const int kslice = l4 >> 5, kslot = (l4 >> 3) & 3, kin = l4 & 7;
#pragma unroll
    for (int it = 0; it < 16; ++it) {
      const int rr = wave + (it << 2);               // row 0..63 (wave-uniform)
      const int R = r0 + rr;
      const int bs = R / KC, k = R - bs * KC;
      int idx = indices[(size_t)bs * KC + k];
      if (idx < 0) idx = 0;
      f32x4 cv = *(const f32x4*)(KB + (size_t)idx * OUT_DIM + l4);
      f32x4 pv = *(const f32x4*)(pred + (size_t)bs * OUT_DIM + l4);
      float* co = cand_out + (size_t)R * 257 + 1 + l4;
      co[0] = cv.x; co[1] = cv.y; co[2] = cv.z; co[3] = cv.w;
      u16x4 dv;
      dv.x = (unsigned short)f2bf(cv.x - pv.x);
      dv.y = (unsigned short)f2bf(cv.y - pv.y);
      dv.z = (unsigned short)f2bf(cv.z - pv.z);
      dv.w = (unsigned short)f2bf(cv.w - pv.w);
      const int rsw = (rr >> 1) & 3;
      *(u16x4*)&Asw[kslice * 2048 + rr * 32 + ((kslot ^ rsw) << 3) + kin] = dv;
    }
  }
  if (tid < 64) red[tid] = 0.f;

  // ---- B staging pointers (dsW1T: 256 rows x 256 K, pre-swizzled src) ------
  const short* pb[4];
#pragma unroll
  for (int i = 0; i < 4; ++i) {
    const int idx2 = i * 256 + tid;
    const int rr = idx2 >> 2, ss = idx2 & 3, gg = ss ^ ((rr >> 1) & 3);
    pb[i] = W1T + (size_t)rr * 256 + gg * 8;
  }
  auto stageB = [&](short* buf, int t) {
#pragma unroll
    for (int i = 0; i < 4; ++i)
      gload16(pb[i] + (t << 5), buf + i * 2048 + wave * 512);
  };

  f32x4 acc[4][4] = {};
  auto computeDS = [&](const short* as, const short* bsrc) {
    s16x8 af[4], bfr[4];
#pragma unroll
    for (int m = 0; m < 4; ++m)
      af[m] = *(const s16x8*)&as[(m * 16 + lrow) * 32 + koff];
#pragma unroll
    for (int n = 0; n < 4; ++n)
      bfr[n] = *(const s16x8*)&bsrc[(wave * 64 + n * 16 + lrow) * 32 + koff];
#pragma unroll
    for (int m = 0; m < 4; ++m)
#pragma unroll
      for (int n = 0; n < 4; ++n)
        asm("v_mfma_f32_16x16x32_bf16 %0, %1, %2, %0"
            : "+v"(acc[m][n]) : "v"(af[m]), "v"(bfr[n]));
  };

  stageB(Bs0, 0);
  __syncthreads();                       // A writes + red init + Bs0 loads
  for (int t = 0; t < 8; t += 2) {
    stageB(Bs1, t + 1);
    computeDS(Asw + t * 2048, Bs0);
    __syncthreads();
    if (t + 2 < 8) stageB(Bs0, t + 2);
    computeDS(Asw + (t + 1) * 2048, Bs1);
    __syncthreads();
  }

  // ---- fused score epilogue -------------------------------------------------
  float w2r[4], b1r[4];
#pragma unroll
  for (int n = 0; n < 4; ++n) {
    const int col = wave * 64 + n * 16 + lrow;
    w2r[n] = w2v[col];
    b1r[n] = b1v[col];
  }
#pragma unroll
  for (int m = 0; m < 4; ++m) {
#pragma unroll
    for (int r2 = 0; r2 < 4; ++r2) {
      float part = 0.f;
#pragma unroll
      for (int n = 0; n < 4; ++n)
        part += fmaxf(acc[m][n][r2] + b1r[n], 0.f) * w2r[n];
      part += __shfl_xor(part, 1);
      part += __shfl_xor(part, 2);
      part += __shfl_xor(part, 4);
      part += __shfl_xor(part, 8);
      if (lrow == 0) atomicAdd(&red[m * 16 + ks * 4 + r2], part);
    }
  }
  __syncthreads();
  if (tid < 64)
    cand_out[(size_t)(r0 + tid) * 257] = red[tid] + b2v[0];
}

extern "C" void kernel_launch(void* const* d_in, const int* in_sizes, int n_in,
                              void* d_out, int out_size, void* d_ws, size_t ws_size,
                              hipStream_t stream) {
  const float* x      = (const float*)d_in[0];
  const float* ctx    = (const float*)d_in[1];
  const int*   indices= (const int*)d_in[2];
  const float* KB     = (const float*)d_in[3];
  const float* W_in   = (const float*)d_in[4];
  const float* b_in   = (const float*)d_in[5];
  const float* Wqkv   = (const float*)d_in[6];
  const float* bqkv   = (const float*)d_in[7];
  const float* Wo     = (const float*)d_in[8];
  const float* bo     = (const float*)d_in[9];
  const float* ln1_g  = (const float*)d_in[10];
  const float* ln1_b  = (const float*)d_in[11];
  const float* W1     = (const float*)d_in[12];
  const float* b1     = (const float*)d_in[13];
  const float* W2     = (const float*)d_in[14];
  const float* b2     = (const float*)d_in[15];
  const float* ln2_g  = (const float*)d_in[16];
  const float* ln2_b  = (const float*)d_in[17];
  const float* W_out  = (const float*)d_in[18];
  const float* b_out  = (const float*)d_in[19];
  const float* ds_W1  = (const float*)d_in[20];
  const float* ds_b1  = (const float*)d_in[21];
  const float* ds_W2  = (const float*)d_in[22];
  const float* ds_b2  = (const float*)d_in[23];
  // d_in[24..27] = cs_* : dead code in reference (del cs)

  char* p = (char*)d_ws;
  auto alloc = [&](size_t bytes) {
    char* q = p;
    p += (bytes + 255) & ~(size_t)255;
    return q;
  };
  short* h    = (short*)alloc((size_t)MPAD * HD * 2);
  short* tmp1 = (short*)alloc((size_t)MPAD * 3 * HD * 2);  // qkv / ff1
  short* tmp2 = (short*)alloc((size_t)MPAD * HD * 2);      // hin / attn-o
  float* part = (float*)alloc((size_t)2 * MPAD * HD * 4);  // split-K partials
  short* WinT  = (short*)alloc((size_t)HD * IN_DIM * 2);
  short* WqkvT = (short*)alloc((size_t)2 * 3 * HD * HD * 2);
  short* WoT   = (short*)alloc((size_t)2 * HD * HD * 2);
  short* W1T   = (short*)alloc((size_t)2 * DFF * HD * 2);
  short* W2T   = (short*)alloc((size_t)2 * HD * DFF * 2);
  short* WoutT = (short*)alloc((size_t)OUT_DIM * HD * 2);
  short* dsW1T = (short*)alloc((size_t)OUT_DIM * OUT_DIM * 2);

  // all weight transposes (f32 -> bf16, N x K) in ONE dispatch
  transpose_all<<<17728, 256, 0, stream>>>(W_in, Wqkv, Wo, W1, W2, W_out, ds_W1,
                                           WinT, WqkvT, WoT, W1T, W2T, WoutT, dsW1T);

  // forward
  build_hin<<<MROWS, 256, 0, stream>>>(x, ctx, tmp2);
  // Win: split-K x2 (528 blocks), reduce+bias+relu -> h (bf16)
  gemm_bt<0, true, short><<<33 * 8 * 2, 256, 0, stream>>>(
      tmp2, WinT, nullptr, nullptr, part, MROWS, 1024, 1024, 33, 8, 8, 512);
  reduce_cast<1, short><<<MROWS, 256, 0, stream>>>(part, b_in, h, 1024, 2);

  for (int l = 0; l < 2; ++l) {
    gemm_bt<0, false, short><<<33 * 24, 256, 0, stream>>>(
        h, WqkvT + (size_t)l * 3072 * 1024, bqkv + l * 3072, tmp1, nullptr,
        MROWS, 3072, 1024, 33, 24, 8, 0);
    attention_mfma<<<258, 256, 0, stream>>>(tmp1, tmp2);
    // Wo: split-K x2, fused reduce + residual + LN -> h
    gemm_bt<0, true, short><<<33 * 8 * 2, 256, 0, stream>>>(
        tmp2, WoT + (size_t)l * 1024 * 1024, nullptr, nullptr, part,
        MROWS, 1024, 1024, 33, 8, 8, 512);
    reduce_ln<<<MROWS, 256, 0, stream>>>(part, bo + l * 1024,
                                         ln1_g + l * 1024, ln1_b + l * 1024, h);
    gemm_bt<1, false, short><<<33 * 16, 256, 0, stream>>>(
        h, W1T + (size_t)l * 2048 * 1024, b1 + l * 2048, tmp1, nullptr,
        MROWS, 2048, 1024, 33, 16, 8, 0);
    // W2: split-K x2 (K=2048 -> 1024 each), fused reduce + residual + LN -> h
    gemm_bt<0, true, short><<<33 * 8 * 2, 256, 0, stream>>>(
        tmp1, W2T + (size_t)l * 1024 * 2048, nullptr, nullptr, part,
        MROWS, 1024, 2048, 33, 8, 4, 1024);
    reduce_ln<<<MROWS, 256, 0, stream>>>(part, b2 + l * 1024,
                                         ln2_g + l * 1024, ln2_b + l * 1024, h);
  }

  float* pred = (float*)d_out;
  float* cand_out = (float*)d_out + (size_t)B_ * S_ * OUT_DIM;

  // Wout: split-K x4 (264 blocks), reduce -> pred (d_out)
  gemm_bt<0, true, float><<<33 * 2 * 4, 256, 0, stream>>>(
      h, WoutT, nullptr, nullptr, part, MROWS, 256, 1024, 33, 2, 8, 256);
  reduce_wout<<<MROWS, 64, 0, stream>>>(part, b_out, pred);

  // fused gather + ds-GEMM + score (640 blocks x 64 rows)
  cand_score<<<NCAND / 64, 256, 0, stream>>>(pred, indices, KB, dsW1T,
                                             ds_b1, ds_W2, ds_b2, cand_out);
}

// Round 14
// 409.385 us; speedup vs baseline: 1.0638x; 1.0638x over previous
//
#include <hip/hip_runtime.h>
#include <hip/hip_bf16.h>

typedef __attribute__((ext_vector_type(4))) float f32x4;
typedef __attribute__((ext_vector_type(8))) short s16x8;
typedef __attribute__((ext_vector_type(4))) unsigned short u16x4;
typedef __attribute__((ext_vector_type(8))) __bf16 bf16x8;

#define B_      32
#define S_      128
#define SEQ     129
#define IN_DIM  1024
#define HD      1024
#define NHEAD   8
#define DH      128
#define OUT_DIM 256
#define KC      10
#define DFF     2048
#define MROWS   (B_*SEQ)     // 4128
#define MPAD    4224         // 33 * 128
#define NCAND   (B_*S_*KC)   // 40960 = 640*64

__device__ __forceinline__ short f2bf(float f) {
  unsigned u = __builtin_bit_cast(unsigned, f);
  u += 0x7FFFu + ((u >> 16) & 1u);   // RNE to bf16
  return (short)(u >> 16);
}
__device__ __forceinline__ float bf2f(short s) {
  return __builtin_bit_cast(float, ((unsigned)(unsigned short)s) << 16);
}
__device__ __forceinline__ void gload16(const short* g, short* l) {
  __builtin_amdgcn_global_load_lds(
      (const __attribute__((address_space(1))) unsigned*)g,
      (__attribute__((address_space(3))) unsigned*)l, 16, 0, 0);
}
// builtin MFMA: compiler-managed hazards (inline asm hid them -> NaN, r11)
__device__ __forceinline__ f32x4 mfma16(s16x8 a, s16x8 b, f32x4 c) {
  return __builtin_amdgcn_mfma_f32_16x16x32_bf16(
      __builtin_bit_cast(bf16x8, a), __builtin_bit_cast(bf16x8, b), c, 0, 0, 0);
}

// ---- prologue: ALL weight transposes (f32 W[K][N] -> bf16 Wt[N][K]) + h_in --
__global__ __launch_bounds__(256) void prologue(
    const float* __restrict__ W_in,  const float* __restrict__ Wqkv,
    const float* __restrict__ Wo,    const float* __restrict__ W1,
    const float* __restrict__ W2,    const float* __restrict__ W_out,
    const float* __restrict__ dsW1,
    short* __restrict__ WinT,  short* __restrict__ WqkvT,
    short* __restrict__ WoT,   short* __restrict__ W1T,
    short* __restrict__ W2T,   short* __restrict__ WoutT,
    short* __restrict__ dsW1T,
    const float* __restrict__ x, const float* __restrict__ ctx,
    short* __restrict__ hin) {
  const int b = blockIdx.x;
  if (b >= 17728) {                     // build_hin part: rows of concat(ctx,x)
    const int r = b - 17728;
    const int bb = r / SEQ, t = r % SEQ;
    const float* src = (t == 0) ? (ctx + (size_t)bb * IN_DIM)
                                : (x + ((size_t)bb * S_ + (t - 1)) * IN_DIM);
    f32x4 v = *(const f32x4*)(src + threadIdx.x * 4);
    u16x4 o;
    o.x = (unsigned short)f2bf(v.x); o.y = (unsigned short)f2bf(v.y);
    o.z = (unsigned short)f2bf(v.z); o.w = (unsigned short)f2bf(v.w);
    *(u16x4*)(hin + (size_t)r * IN_DIM + threadIdx.x * 4) = o;
    return;
  }
  const float* src; short* dst; int K, N, local;
  if (b < 1024)       { src = W_in;  dst = WinT;  K = 1024; N = 1024; local = b; }
  else if (b < 7168)  { int l = (b - 1024) / 3072; local = (b - 1024) % 3072;
                        src = Wqkv + (size_t)l * 1024 * 3072;
                        dst = WqkvT + (size_t)l * 3072 * 1024; K = 1024; N = 3072; }
  else if (b < 9216)  { int l = (b - 7168) / 1024; local = (b - 7168) % 1024;
                        src = Wo + (size_t)l * 1024 * 1024;
                        dst = WoT + (size_t)l * 1024 * 1024; K = 1024; N = 1024; }
  else if (b < 13312) { int l = (b - 9216) / 2048; local = (b - 9216) % 2048;
                        src = W1 + (size_t)l * 1024 * 2048;
                        dst = W1T + (size_t)l * 2048 * 1024; K = 1024; N = 2048; }
  else if (b < 17408) { int l = (b - 13312) / 2048; local = (b - 13312) % 2048;
                        src = W2 + (size_t)l * 2048 * 1024;
                        dst = W2T + (size_t)l * 1024 * 2048; K = 2048; N = 1024; }
  else if (b < 17664) { local = b - 17408; src = W_out; dst = WoutT; K = 1024; N = 256; }
  else                { local = b - 17664; src = dsW1;  dst = dsW1T; K = 256;  N = 256; }
  const int tilesX = N >> 5;
  const int n0 = (local % tilesX) << 5, k0 = (local / tilesX) << 5;

  __shared__ float tile[32][33];
  const int tx = threadIdx.x & 31, ty = threadIdx.x >> 5;  // 32 x 8
#pragma unroll
  for (int i = 0; i < 4; ++i)
    tile[ty + i * 8][tx] = src[(size_t)(k0 + ty + i * 8) * N + n0 + tx];
  __syncthreads();
#pragma unroll
  for (int i = 0; i < 4; ++i)
    dst[(size_t)(n0 + ty + i * 8) * K + k0 + tx] = f2bf(tile[tx][ty + i * 8]);
}

// ---------------- GEMM: C[M][N] = A[M][K](bf16) * Bt[N][K](bf16) + bias ------
// 128x128 tile, 4 waves, BK=32, 2-phase LDS double-buffer via global_load_lds
// with pre-swizzled source. XCD-chunked (m204) + groupM order.
// SPLIT=true: grid gm*gn*nsplit; each split computes kper K-columns and
// writes BF16 partials to Pb[split][MPAD][N] (no bias) — halves partial
// traffic vs f32; same rounding class as the non-split bf16 C-write.
template <int EPI, bool SPLIT, typename OutT>
__global__ __launch_bounds__(256) void gemm_bt(const short* __restrict__ A,
                                               const short* __restrict__ Bt,
                                               const float* __restrict__ bias,
                                               OutT* __restrict__ C,
                                               short* __restrict__ Pb,
                                               int M, int N, int K,
                                               int gm, int gn, int groupM,
                                               int kper) {
  __shared__ alignas(16) short As0[4096], As1[4096];  // 128 rows x 32 bf16
  __shared__ alignas(16) short Bs0[4096], Bs1[4096];
  const int tid = threadIdx.x;
  const int lane = tid & 63, wave = tid >> 6;
  const int wr = wave >> 1, wc = wave & 1;          // 2x2 waves, 64x64 each

  // --- split decode (split-major) + XCD-chunked bijective remap (m204) ------
  const int nwg = gm * gn;
  int orig = blockIdx.x;
  int split = 0;
  if constexpr (SPLIT) { split = orig / nwg; orig %= nwg; }
  const int xcd = orig & 7, kk = orig >> 3;
  const int q = nwg >> 3, r = nwg & 7;
  const int wg = (xcd < r ? xcd * (q + 1) : r * (q + 1) + (xcd - r) * q) + kk;
  const int tpg = groupM * gn;
  const int grp = wg / tpg, rem = wg % tpg;
  const int g0 = grp * groupM;
  const int gsz = (groupM < gm - g0) ? groupM : (gm - g0);
  const int bm = (g0 + rem % gsz) * 128;
  const int bn = (rem / gsz) * 128;
  const int kbase = SPLIT ? split * kper : 0;

  // staging: pre-swizzled global source, linear LDS dest (global_load_lds).
  const short* pa[2];
  const short* pb[2];
#pragma unroll
  for (int i = 0; i < 2; ++i) {
    const int idx = i * 256 + tid;
    const int rr = idx >> 2, ss = idx & 3, gg = ss ^ ((rr >> 1) & 3);
    pa[i] = A + (size_t)(bm + rr) * K + kbase + gg * 8;
    pb[i] = Bt + (size_t)(bn + rr) * K + kbase + gg * 8;
  }

  auto stage = [&](short* aBuf, short* bBuf, int t) {
    const int kofs = t << 5;
    gload16(pa[0] + kofs, aBuf + wave * 512);
    gload16(pa[1] + kofs, aBuf + 2048 + wave * 512);
    gload16(pb[0] + kofs, bBuf + wave * 512);
    gload16(pb[1] + kofs, bBuf + 2048 + wave * 512);
  };

  // fragment reads (swizzled): row rr, k-slot ks -> shorts rr*32 + ((ks^sx)<<3)
  const int lrow = lane & 15, ks = lane >> 4;
  const int sx = (lrow >> 1) & 3;
  const int koff = ((ks ^ sx) << 3);

  f32x4 acc[4][4] = {};

  auto compute = [&](const short* as, const short* bs) {
    s16x8 af[4], bfr[4];
#pragma unroll
    for (int m = 0; m < 4; ++m)
      af[m] = *(const s16x8*)&as[(wr * 64 + m * 16 + lrow) * 32 + koff];
#pragma unroll
    for (int n = 0; n < 4; ++n)
      bfr[n] = *(const s16x8*)&bs[(wc * 64 + n * 16 + lrow) * 32 + koff];
#pragma unroll
    for (int m = 0; m < 4; ++m)
#pragma unroll
      for (int n = 0; n < 4; ++n)
        asm("v_mfma_f32_16x16x32_bf16 %0, %1, %2, %0"
            : "+v"(acc[m][n]) : "v"(af[m]), "v"(bfr[n]));
  };

  const int NT = (SPLIT ? kper : K) >> 5;   // even at all call sites
  stage(As0, Bs0, 0);
  __syncthreads();
  for (int t = 0; t < NT; t += 2) {
    stage(As1, Bs1, t + 1);              // prefetch overlaps compute below
    compute(As0, Bs0);
    __syncthreads();
    if (t + 2 < NT) stage(As0, Bs0, t + 2);
    compute(As1, Bs1);
    __syncthreads();
  }

  const int lg4 = ks << 2;
#pragma unroll
  for (int n = 0; n < 4; ++n) {
    const int col = bn + wc * 64 + n * 16 + lrow;
    const float bvx = SPLIT ? 0.f : bias[col];
#pragma unroll
    for (int m = 0; m < 4; ++m) {
#pragma unroll
      for (int r2 = 0; r2 < 4; ++r2) {
        const int row = bm + wr * 64 + m * 16 + lg4 + r2;
        if constexpr (SPLIT) {
          Pb[((size_t)split * MPAD + row) * N + col] = f2bf(acc[m][n][r2]);
        } else {
          if (row < M) {
            float v = acc[m][n][r2] + bvx;
            if (EPI == 1) v = fmaxf(v, 0.f);
            if constexpr (__is_same(OutT, float)) {
              C[(size_t)row * N + col] = v;
            } else {
              C[(size_t)row * N + col] = f2bf(v);
            }
          }
        }
      }
    }
  }
}

// ---------------- reduce bf16 split-K partials: out = f(sum_s P[s] + bias) ---
template <int EPI>
__global__ __launch_bounds__(256) void reduce_cast(const short* __restrict__ P,
                                                   const float* __restrict__ bias,
                                                   short* __restrict__ out,
                                                   int N, int nsplit) {
  const int row = blockIdx.x;            // 0..MROWS-1
  for (int c = threadIdx.x * 4; c < N; c += 1024) {
    f32x4 s = *(const f32x4*)(bias + c);
    for (int sp = 0; sp < nsplit; ++sp) {
      u16x4 pv = *(const u16x4*)(P + ((size_t)sp * MPAD + row) * N + c);
      s.x += bf2f((short)pv.x); s.y += bf2f((short)pv.y);
      s.z += bf2f((short)pv.z); s.w += bf2f((short)pv.w);
    }
    if (EPI == 1) {
      s.x = fmaxf(s.x, 0.f); s.y = fmaxf(s.y, 0.f);
      s.z = fmaxf(s.z, 0.f); s.w = fmaxf(s.w, 0.f);
    }
    u16x4 y;
    y.x = (unsigned short)f2bf(s.x); y.y = (unsigned short)f2bf(s.y);
    y.z = (unsigned short)f2bf(s.z); y.w = (unsigned short)f2bf(s.w);
    *(u16x4*)(out + (size_t)row * N + c) = y;
  }
}

// ---- fused: h = LN(h + (P0+P1 + bias)) * g + b  (bf16 partials + add+LN) ----
__global__ __launch_bounds__(256) void reduce_ln(const short* __restrict__ P,
                                                 const float* __restrict__ bias,
                                                 const float* __restrict__ g,
                                                 const float* __restrict__ bb,
                                                 short* __restrict__ h) {
  const int r = blockIdx.x, tid = threadIdx.x;
  f32x4 s = *(const f32x4*)(bias + tid * 4);
  {
    u16x4 p0 = *(const u16x4*)(P + (size_t)r * 1024 + tid * 4);
    u16x4 p1 = *(const u16x4*)(P + ((size_t)MPAD + r) * 1024 + tid * 4);
    s.x += bf2f((short)p0.x) + bf2f((short)p1.x);
    s.y += bf2f((short)p0.y) + bf2f((short)p1.y);
    s.z += bf2f((short)p0.z) + bf2f((short)p1.z);
    s.w += bf2f((short)p0.w) + bf2f((short)p1.w);
  }
  const u16x4 hv = *(const u16x4*)(h + (size_t)r * 1024 + tid * 4);
  float s0 = s.x + bf2f((short)hv.x);
  float s1 = s.y + bf2f((short)hv.y);
  float s2 = s.z + bf2f((short)hv.z);
  float s3 = s.w + bf2f((short)hv.w);
  float ls = s0 + s1 + s2 + s3;
  float l2 = s0 * s0 + s1 * s1 + s2 * s2 + s3 * s3;
#pragma unroll
  for (int off = 32; off > 0; off >>= 1) {
    ls += __shfl_down(ls, off);
    l2 += __shfl_down(l2, off);
  }
  __shared__ float red[8];
  const int wave = tid >> 6, lane = tid & 63;
  if (lane == 0) { red[wave * 2] = ls; red[wave * 2 + 1] = l2; }
  __syncthreads();
  if (tid == 0) {
    float a = 0.f, b2 = 0.f;
    for (int w = 0; w < 4; ++w) { a += red[w * 2]; b2 += red[w * 2 + 1]; }
    red[0] = a; red[1] = b2;
  }
  __syncthreads();
  const float mean = red[0] * (1.f / HD);
  const float var  = red[1] * (1.f / HD) - mean * mean;
  const float inv  = rsqrtf(var + 1e-5f);
  const f32x4 gv = *(const f32x4*)(g + tid * 4);
  const f32x4 bv = *(const f32x4*)(bb + tid * 4);
  u16x4 y;
  y.x = (unsigned short)f2bf((s0 - mean) * inv * gv.x + bv.x);
  y.y = (unsigned short)f2bf((s1 - mean) * inv * gv.y + bv.y);
  y.z = (unsigned short)f2bf((s2 - mean) * inv * gv.z + bv.z);
  y.w = (unsigned short)f2bf((s3 - mean) * inv * gv.w + bv.w);
  *(u16x4*)(h + (size_t)r * 1024 + tid * 4) = y;
}

// ---- Wout reduce (4 bf16 splits, N=256) -> pred (d_out, f32) ----------------
__global__ __launch_bounds__(64) void reduce_wout(const short* __restrict__ P,
                                                  const float* __restrict__ bias,
                                                  float* __restrict__ pred) {
  const int r = blockIdx.x;
  const int b = r / SEQ, t = r % SEQ;
  if (t == 0) return;                    // ctx row: not part of pred
  const int c = threadIdx.x * 4;
  f32x4 s = *(const f32x4*)(bias + c);
#pragma unroll
  for (int sp = 0; sp < 4; ++sp) {
    u16x4 pv = *(const u16x4*)(P + ((size_t)sp * MPAD + r) * 256 + c);
    s.x += bf2f((short)pv.x); s.y += bf2f((short)pv.y);
    s.z += bf2f((short)pv.z); s.w += bf2f((short)pv.w);
  }
  *(f32x4*)(pred + ((size_t)b * S_ + (t - 1)) * 256 + c) = s;
}

// ---------------- MFMA attention: ONE WAVE per (t, head), no barriers -------
__global__ __launch_bounds__(256) void attention_mfma(const short* __restrict__ qkv,
                                                      short* __restrict__ o) {
  __shared__ alignas(16) short qs[4][32][136];
  __shared__ alignas(16) short ksb[4][32][136];
  __shared__ alignas(16) short vsb[4][32][136];
  __shared__ float psb[4][32][33];
  const int tid = threadIdx.x, lane = tid & 63, w = tid >> 6;
  const int gw = blockIdx.x * 4 + w;                 // 0..1031
  const int t = gw >> 3, hd = gw & 7;
  short (*q)[136] = qs[w];
  short (*k)[136] = ksb[w];
  short (*v)[136] = vsb[w];
  float (*ps)[33] = psb[w];

  // load Q,K,V rows (bb = batch 0..31) for this (t, head)
#pragma unroll
  for (int c = lane; c < 512; c += 64) {             // 8 iters
    const int bb = c >> 4, d8 = (c & 15) << 3;
    const size_t base = ((size_t)(bb * SEQ + t)) * (3 * HD) + hd * DH + d8;
    *(s16x8*)&q[bb][d8] = *(const s16x8*)(qkv + base);
    *(s16x8*)&k[bb][d8] = *(const s16x8*)(qkv + base + HD);
    *(s16x8*)&v[bb][d8] = *(const s16x8*)(qkv + base + 2 * HD);
  }

  const int lrow = lane & 15, ksl = lane >> 4;
  const float scale = 0.08838834764831845f;          // 1/sqrt(128)

  // ---- QK^T: C[i][j] = sum_d Q[i][d] K[j][d]  (M=32, N=32, K=128) ----------
  f32x4 pacc[2][2] = {};
#pragma unroll
  for (int kst = 0; kst < 4; ++kst) {
    s16x8 aq[2], bk[2];
#pragma unroll
    for (int m = 0; m < 2; ++m)
      aq[m] = *(const s16x8*)&q[m * 16 + lrow][kst * 32 + ksl * 8];
#pragma unroll
    for (int n = 0; n < 2; ++n)
      bk[n] = *(const s16x8*)&k[n * 16 + lrow][kst * 32 + ksl * 8];
#pragma unroll
    for (int m = 0; m < 2; ++m)
#pragma unroll
      for (int n = 0; n < 2; ++n)
        pacc[m][n] = mfma16(aq[m], bk[n], pacc[m][n]);
  }
#pragma unroll
  for (int m = 0; m < 2; ++m)
#pragma unroll
    for (int n = 0; n < 2; ++n)
#pragma unroll
      for (int r = 0; r < 4; ++r)
        ps[m * 16 + ksl * 4 + r][n * 16 + lrow] = pacc[m][n][r] * scale;

  // ---- softmax per row (lanes 0..31, intra-wave ordered) -------------------
  if (lane < 32) {
    float mx = -1e30f;
#pragma unroll
    for (int j = 0; j < 32; ++j) mx = fmaxf(mx, ps[lane][j]);
    float sum = 0.f;
    float e[32];
#pragma unroll
    for (int j = 0; j < 32; ++j) { e[j] = __expf(ps[lane][j] - mx); sum += e[j]; }
    const float inv = 1.f / sum;
#pragma unroll
    for (int j = 0; j < 32; ++j) ps[lane][j] = e[j] * inv;
  }

  // ---- PV: O[i][d] = sum_j P[i][j] V[j][d]  (M=32, N=128, K=32) ------------
  s16x8 pa[2];
#pragma unroll
  for (int m = 0; m < 2; ++m) {
    const float* pr = &ps[m * 16 + lrow][ksl * 8];
#pragma unroll
    for (int j = 0; j < 8; ++j) pa[m][j] = f2bf(pr[j]);
  }
  f32x4 oacc[2][8] = {};
#pragma unroll
  for (int n = 0; n < 8; ++n) {
    s16x8 bv;
#pragma unroll
    for (int r = 0; r < 8; ++r)
      bv[r] = v[ksl * 8 + r][n * 16 + lrow];
#pragma unroll
    for (int m = 0; m < 2; ++m)
      oacc[m][n] = mfma16(pa[m], bv, oacc[m][n]);
  }
#pragma unroll
  for (int m = 0; m < 2; ++m)
#pragma unroll
    for (int n = 0; n < 8; ++n)
#pragma unroll
      for (int r = 0; r < 4; ++r) {
        const int i = m * 16 + ksl * 4 + r;
        const int d = n * 16 + lrow;
        o[((size_t)(i * SEQ + t)) * HD + hd * DH + d] = f2bf(oacc[m][n][r]);
      }
}

// ---- fused candidate scorer: gather KB rows, write cand_out[..,1:],
//      d = cand - pred -> swizzled LDS, t1 = relu(d @ dsW1 + b1) (MFMA),
//      cand_out[row*257] = t1 . w2 + b2. Block = 64 cand rows, 4 waves. ------
__global__ __launch_bounds__(256) void cand_score(
    const float* __restrict__ pred, const int* __restrict__ indices,
    const float* __restrict__ KB, const short* __restrict__ W1T,
    const float* __restrict__ b1v, const float* __restrict__ w2v,
    const float* __restrict__ b2v, float* __restrict__ cand_out) {
  __shared__ alignas(16) short Asw[8 * 2048];        // [kslice][64 rows][32] 32KB
  __shared__ alignas(16) short Bs0[8192], Bs1[8192]; // 16KB each
  __shared__ float red[64];
  const int tid = threadIdx.x;
  const int lane = tid & 63, wave = tid >> 6;        // 4 waves; wave = col-block
  const int lrow = lane & 15, ks = lane >> 4;
  const int sx = (lrow >> 1) & 3;
  const int koff = ((ks ^ sx) << 3);
  const int r0 = blockIdx.x << 6;

  // ---- gather + diff + swizzled A write + cand_out write (coalesced) ------
  {
    const int l4 = lane << 2;                        // col base 0..252
    const int kslice = l4 >> 5, kslot = (l4 >> 3) & 3, kin = l4 & 7;
#pragma unroll
    for (int it = 0; it < 16; ++it) {
      const int rr = wave + (it << 2);               // row 0..63 (wave-uniform)
      const int R = r0 + rr;
      const int bs = R / KC, k = R - bs * KC;
      int idx = indices[(size_t)bs * KC + k];
      if (idx < 0) idx = 0;
      f32x4 cv = *(const f32x4*)(KB + (size_t)idx * OUT_DIM + l4);
      f32x4 pv = *(const f32x4*)(pred + (size_t)bs * OUT_DIM + l4);
      float* co = cand_out + (size_t)R * 257 + 1 + l4;
      co[0] = cv.x; co[1] = cv.y; co[2] = cv.z; co[3] = cv.w;
      u16x4 dv;
      dv.x = (unsigned short)f2bf(cv.x - pv.x);
      dv.y = (unsigned short)f2bf(cv.y - pv.y);
      dv.z = (unsigned short)f2bf(cv.z - pv.z);
      dv.w = (unsigned short)f2bf(cv.w - pv.w);
      const int rsw = (rr >> 1) & 3;
      *(u16x4*)&Asw[kslice * 2048 + rr * 32 + ((kslot ^ rsw) << 3) + kin] = dv;
    }
  }
  if (tid < 64) red[tid] = 0.f;

  // ---- B staging pointers (dsW1T: 256 rows x 256 K, pre-swizzled src) ------
  const short* pb[4];
#pragma unroll
  for (int i = 0; i < 4; ++i) {
    const int idx2 = i * 256 + tid;
    const int rr = idx2 >> 2, ss = idx2 & 3, gg = ss ^ ((rr >> 1) & 3);
    pb[i] = W1T + (size_t)rr * 256 + gg * 8;
  }
  auto stageB = [&](short* buf, int t) {
#pragma unroll
    for (int i = 0; i < 4; ++i)
      gload16(pb[i] + (t << 5), buf + i * 2048 + wave * 512);
  };

  f32x4 acc[4][4] = {};
  auto computeDS = [&](const short* as, const short* bsrc) {
    s16x8 af[4], bfr[4];
#pragma unroll
    for (int m = 0; m < 4; ++m)
      af[m] = *(const s16x8*)&as[(m * 16 + lrow) * 32 + koff];
#pragma unroll
    for (int n = 0; n < 4; ++n)
      bfr[n] = *(const s16x8*)&bsrc[(wave * 64 + n * 16 + lrow) * 32 + koff];
#pragma unroll
    for (int m = 0; m < 4; ++m)
#pragma unroll
      for (int n = 0; n < 4; ++n)
        asm("v_mfma_f32_16x16x32_bf16 %0, %1, %2, %0"
            : "+v"(acc[m][n]) : "v"(af[m]), "v"(bfr[n]));
  };

  stageB(Bs0, 0);
  __syncthreads();                       // A writes + red init + Bs0 loads
  for (int t = 0; t < 8; t += 2) {
    stageB(Bs1, t + 1);
    computeDS(Asw + t * 2048, Bs0);
    __syncthreads();
    if (t + 2 < 8) stageB(Bs0, t + 2);
    computeDS(Asw + (t + 1) * 2048, Bs1);
    __syncthreads();
  }

  // ---- fused score epilogue -------------------------------------------------
  float w2r[4], b1r[4];
#pragma unroll
  for (int n = 0; n < 4; ++n) {
    const int col = wave * 64 + n * 16 + lrow;
    w2r[n] = w2v[col];
    b1r[n] = b1v[col];
  }
#pragma unroll
  for (int m = 0; m < 4; ++m) {
#pragma unroll
    for (int r2 = 0; r2 < 4; ++r2) {
      float part = 0.f;
#pragma unroll
      for (int n = 0; n < 4; ++n)
        part += fmaxf(acc[m][n][r2] + b1r[n], 0.f) * w2r[n];
      part += __shfl_xor(part, 1);
      part += __shfl_xor(part, 2);
      part += __shfl_xor(part, 4);
      part += __shfl_xor(part, 8);
      if (lrow == 0) atomicAdd(&red[m * 16 + ks * 4 + r2], part);
    }
  }
  __syncthreads();
  if (tid < 64)
    cand_out[(size_t)(r0 + tid) * 257] = red[tid] + b2v[0];
}

extern "C" void kernel_launch(void* const* d_in, const int* in_sizes, int n_in,
                              void* d_out, int out_size, void* d_ws, size_t ws_size,
                              hipStream_t stream) {
  const float* x      = (const float*)d_in[0];
  const float* ctx    = (const float*)d_in[1];
  const int*   indices= (const int*)d_in[2];
  const float* KB     = (const float*)d_in[3];
  const float* W_in   = (const float*)d_in[4];
  const float* b_in   = (const float*)d_in[5];
  const float* Wqkv   = (const float*)d_in[6];
  const float* bqkv   = (const float*)d_in[7];
  const float* Wo     = (const float*)d_in[8];
  const float* bo     = (const float*)d_in[9];
  const float* ln1_g  = (const float*)d_in[10];
  const float* ln1_b  = (const float*)d_in[11];
  const float* W1     = (const float*)d_in[12];
  const float* b1     = (const float*)d_in[13];
  const float* W2     = (const float*)d_in[14];
  const float* b2     = (const float*)d_in[15];
  const float* ln2_g  = (const float*)d_in[16];
  const float* ln2_b  = (const float*)d_in[17];
  const float* W_out  = (const float*)d_in[18];
  const float* b_out  = (const float*)d_in[19];
  const float* ds_W1  = (const float*)d_in[20];
  const float* ds_b1  = (const float*)d_in[21];
  const float* ds_W2  = (const float*)d_in[22];
  const float* ds_b2  = (const float*)d_in[23];
  // d_in[24..27] = cs_* : dead code in reference (del cs)

  char* p = (char*)d_ws;
  auto alloc = [&](size_t bytes) {
    char* q = p;
    p += (bytes + 255) & ~(size_t)255;
    return q;
  };
  short* h    = (short*)alloc((size_t)MPAD * HD * 2);
  short* tmp1 = (short*)alloc((size_t)MPAD * 3 * HD * 2);  // qkv / ff1
  short* tmp2 = (short*)alloc((size_t)MPAD * HD * 2);      // hin / attn-o
  short* part = (short*)alloc((size_t)2 * MPAD * HD * 2);  // bf16 split partials
  short* WinT  = (short*)alloc((size_t)HD * IN_DIM * 2);
  short* WqkvT = (short*)alloc((size_t)2 * 3 * HD * HD * 2);
  short* WoT   = (short*)alloc((size_t)2 * HD * HD * 2);
  short* W1T   = (short*)alloc((size_t)2 * DFF * HD * 2);
  short* W2T   = (short*)alloc((size_t)2 * HD * DFF * 2);
  short* WoutT = (short*)alloc((size_t)OUT_DIM * HD * 2);
  short* dsW1T = (short*)alloc((size_t)OUT_DIM * OUT_DIM * 2);

  // weight transposes + h_in build in ONE dispatch
  prologue<<<17728 + MROWS, 256, 0, stream>>>(
      W_in, Wqkv, Wo, W1, W2, W_out, ds_W1,
      WinT, WqkvT, WoT, W1T, W2T, WoutT, dsW1T, x, ctx, tmp2);

  // Win: split-K x2 (528 blocks), reduce+bias+relu -> h (bf16)
  gemm_bt<0, true, short><<<33 * 8 * 2, 256, 0, stream>>>(
      tmp2, WinT, nullptr, nullptr, part, MROWS, 1024, 1024, 33, 8, 8, 512);
  reduce_cast<1><<<MROWS, 256, 0, stream>>>(part, b_in, h, 1024, 2);

  for (int l = 0; l < 2; ++l) {
    gemm_bt<0, false, short><<<33 * 24, 256, 0, stream>>>(
        h, WqkvT + (size_t)l * 3072 * 1024, bqkv + l * 3072, tmp1, nullptr,
        MROWS, 3072, 1024, 33, 24, 8, 0);
    attention_mfma<<<258, 256, 0, stream>>>(tmp1, tmp2);
    // Wo: split-K x2, fused reduce + residual + LN -> h
    gemm_bt<0, true, short><<<33 * 8 * 2, 256, 0, stream>>>(
        tmp2, WoT + (size_t)l * 1024 * 1024, nullptr, nullptr, part,
        MROWS, 1024, 1024, 33, 8, 8, 512);
    reduce_ln<<<MROWS, 256, 0, stream>>>(part, bo + l * 1024,
                                         ln1_g + l * 1024, ln1_b + l * 1024, h);
    gemm_bt<1, false, short><<<33 * 16, 256, 0, stream>>>(
        h, W1T + (size_t)l * 2048 * 1024, b1 + l * 2048, tmp1, nullptr,
        MROWS, 2048, 1024, 33, 16, 8, 0);
    // W2: split-K x2 (K=2048 -> 1024 each), fused reduce + residual + LN -> h
    gemm_bt<0, true, short><<<33 * 8 * 2, 256, 0, stream>>>(
        tmp1, W2T + (size_t)l * 1024 * 2048, nullptr, nullptr, part,
        MROWS, 1024, 2048, 33, 8, 4, 1024);
    reduce_ln<<<MROWS, 256, 0, stream>>>(part, b2 + l * 1024,
                                         ln2_g + l * 1024, ln2_b + l * 1024, h);
  }

  float* pred = (float*)d_out;
  float* cand_out = (float*)d_out + (size_t)B_ * S_ * OUT_DIM;

  // Wout: split-K x4 (264 blocks, bf16 partials), reduce -> pred (d_out)
  gemm_bt<0, true, float><<<33 * 2 * 4, 256, 0, stream>>>(
      h, WoutT, nullptr, nullptr, part, MROWS, 256, 1024, 33, 2, 8, 256);
  reduce_wout<<<MROWS, 64, 0, stream>>>(part, b_out, pred);

  // fused gather + ds-GEMM + score (640 blocks x 64 rows)
  cand_score<<<NCAND / 64, 256, 0, stream>>>(pred, indices, KB, dsW1T,
                                             ds_b1, ds_W2, ds_b2, cand_out);
}